// Round 17
// baseline (208.187 us; speedup 1.0000x reference)
//
#include <hip/hip_runtime.h>
#include <math.h>

#define DIN  128
#define DOUT 64
#define PROWS 128   // proj tile rows (halves per-output staging/barrier cost)
#define KS   32     // k-slab depth
#define XSP  36     // x-slab pitch floats (32+4): 144B = 16B-mult, rows spread banks
#define BSH  5      // bucket = dst >> 5 (32 dsts/bucket)
#define BMSK 31
#define BCAP 1344   // entries/bucket: mean 1024, sd ~32 -> +10 sigma pad (mult of 64)

__device__ inline unsigned short f2bf(float f) {          // RNE bf16 round
    unsigned u = __float_as_uint(f);
    u += 0x7fffu + ((u >> 16) & 1u);
    return (unsigned short)(u >> 16);
}
__device__ inline float bflo(unsigned u) { return __uint_as_float(u << 16); }
__device__ inline float bfhi(unsigned u) { return __uint_as_float(u & 0xffff0000u); }

// ---------------------------------------------------------------------------
// K1 fused build_k.  Fill branch: R15 body (2048 bucket counters).
// Proj branch: 128x64 tile, thread owns 8 rows x 4 ch; R13 k-slab staging.
// R17 FIX: R16's host-side P=ceil(total/nFill)=3 violated the fill-coverage
// condition total >= (nFill-1)*P+1 -> only 652 of 782 fill blocks ran and
// ~266K edges were dropped (absmax 0.78).  P=floor(total/nFill)=2 gives
// exactly 782 fill blocks (even b<1564) and a dense proj index (enumerated).
// Per-output k order and FMA nesting unchanged -> y/z bit-identical to R15.
// ---------------------------------------------------------------------------
__global__ void __launch_bounds__(256) build_k(
    const int* __restrict__ ei, unsigned* __restrict__ gTail,
    int* __restrict__ bucketBuf,
    const float* __restrict__ x, const float* __restrict__ Wl,
    const float* __restrict__ bl, const float* __restrict__ Wr,
    unsigned short* __restrict__ y, float* __restrict__ zout,
    int E, int nFill, int P, int nyb, int n_src, int n_dst, int nB)
{
    __shared__ float s_mem[PROWS * XSP + KS * DOUT];   // 4608+2048 floats = 26624B
    const int b = blockIdx.x;
    const int fq = b / P;
    const bool isFill = ((b % P) == 0) && (fq < nFill);

    if (isFill) {
        int* s_i  = (int*)s_mem;     // 6144 ints used (24KB <= 26.6KB)
        int* lcnt = s_i;             // [2048]
        int* lpos = s_i + 2048;      // [2048]
        int* s_gb = s_i + 4096;      // [2048]
        const int t = threadIdx.x;
        const int myb = (fq * 256 + t) * 8;
        const bool full = (myb + 8 <= E);
        const bool any  = (myb < E);
        int4 sa, sb4, da, db;
        if (full) {
            sa  = *(const int4*)(ei + myb);
            sb4 = *(const int4*)(ei + myb + 4);
            da  = *(const int4*)(ei + E + myb);
            db  = *(const int4*)(ei + E + myb + 4);
        }
        #pragma unroll
        for (int k = 0; k < 8; ++k) { lcnt[t + k * 256] = 0; lpos[t + k * 256] = 0; }
        __syncthreads();
        if (full) {
            atomicAdd(&lcnt[da.x >> BSH], 1); atomicAdd(&lcnt[da.y >> BSH], 1);
            atomicAdd(&lcnt[da.z >> BSH], 1); atomicAdd(&lcnt[da.w >> BSH], 1);
            atomicAdd(&lcnt[db.x >> BSH], 1); atomicAdd(&lcnt[db.y >> BSH], 1);
            atomicAdd(&lcnt[db.z >> BSH], 1); atomicAdd(&lcnt[db.w >> BSH], 1);
        } else if (any) {
            for (int i = myb; i < E && i < myb + 8; ++i)
                atomicAdd(&lcnt[ei[E + i] >> BSH], 1);
        }
        __syncthreads();
        for (int bk = t; bk < nB; bk += 256)
            s_gb[bk] = (int)atomicAdd(&gTail[bk], (unsigned)lcnt[bk]);
        __syncthreads();
#define PLACE(S, D) { int bk = (D) >> BSH; int p = atomicAdd(&lpos[bk], 1);          \
                      unsigned pos = (unsigned)(s_gb[bk] + p);                        \
                      if (pos < BCAP) bucketBuf[(size_t)bk * BCAP + pos] =            \
                          ((S) << BSH) | ((D) & BMSK); }
        if (full) {
            PLACE(sa.x,  da.x) PLACE(sa.y,  da.y) PLACE(sa.z,  da.z) PLACE(sa.w,  da.w)
            PLACE(sb4.x, db.x) PLACE(sb4.y, db.y) PLACE(sb4.z, db.z) PLACE(sb4.w, db.w)
        } else if (any) {
            for (int i = myb; i < E && i < myb + 8; ++i) {
                int s = ei[i], d = ei[E + i];
                PLACE(s, d)
            }
        }
#undef PLACE
        return;
    }

    // ---- projection: 128 rows x 64 ch per block, k-slab staged ----
    const int fillsBefore = (fq + 1 < nFill) ? (fq + 1) : nFill;
    const int pb = b - fillsBefore;            // dense proj index
    const int t  = threadIdx.x;
    const bool isY = (pb < nyb);
    const int rowBase = (isY ? pb : pb - nyb) * PROWS;
    const int nRows = isY ? n_src : n_dst;
    const float* __restrict__ W = isY ? Wl : Wr;

    float* s_xs = s_mem;                       // [128][XSP]
    float* s_ws = s_mem + PROWS * XSP;         // [KS][DOUT]

    const int cg = t & 15;                     // channel quad: 4cg..4cg+3
    const int rg = t >> 4;                     // row group: rows 8rg..8rg+7
    const int r0 = rg * 8;

    float4 acc0 = {0.f,0.f,0.f,0.f};
    float4 acc1 = {0.f,0.f,0.f,0.f};
    float4 acc2 = {0.f,0.f,0.f,0.f};
    float4 acc3 = {0.f,0.f,0.f,0.f};
    float4 acc4 = {0.f,0.f,0.f,0.f};
    float4 acc5 = {0.f,0.f,0.f,0.f};
    float4 acc6 = {0.f,0.f,0.f,0.f};
    float4 acc7 = {0.f,0.f,0.f,0.f};

#define ROWFMA(acc, xv)                                                                     \
    acc.x = fmaf(xv.w, w3.x, fmaf(xv.z, w2.x, fmaf(xv.y, w1.x, fmaf(xv.x, w0.x, acc.x)))); \
    acc.y = fmaf(xv.w, w3.y, fmaf(xv.z, w2.y, fmaf(xv.y, w1.y, fmaf(xv.x, w0.y, acc.y)))); \
    acc.z = fmaf(xv.w, w3.z, fmaf(xv.z, w2.z, fmaf(xv.y, w1.z, fmaf(xv.x, w0.z, acc.z)))); \
    acc.w = fmaf(xv.w, w3.w, fmaf(xv.z, w2.w, fmaf(xv.y, w1.w, fmaf(xv.x, w0.w, acc.w))));

    for (int k0 = 0; k0 < DIN; k0 += KS) {
        // stage x slab: 128 rows x 32 k = 1024 float4 (8 lanes x 128B per row)
        {
            const float* xs = x + (size_t)rowBase * DIN + k0;
            #pragma unroll
            for (int j = 0; j < 4; ++j) {
                int fi = t + 256 * j;          // 0..1023
                int row = fi >> 3, c4 = fi & 7;
                if (rowBase + row < nRows) {
                    float4 v = *(const float4*)(xs + (size_t)row * DIN + c4 * 4);
                    *(float4*)(&s_xs[row * XSP + c4 * 4]) = v;
                }
            }
            // stage w slab: 32 k x 64 ch = 512 float4 (16 lanes x 256B per k)
            const float* ws = W + (size_t)k0 * DOUT;
            #pragma unroll
            for (int j = 0; j < 2; ++j) {
                int fi = t + 256 * j;
                int row = fi >> 4, c4 = fi & 15;
                float4 v = *(const float4*)(ws + row * DOUT + c4 * 4);
                *(float4*)(&s_ws[row * DOUT + c4 * 4]) = v;
            }
        }
        __syncthreads();

        const float* wp = s_ws + cg * 4;
        #pragma unroll 2
        for (int k = 0; k < KS; k += 4) {
            float4 w0 = *(const float4*)(wp + (k + 0) * DOUT);
            float4 w1 = *(const float4*)(wp + (k + 1) * DOUT);
            float4 w2 = *(const float4*)(wp + (k + 2) * DOUT);
            float4 w3 = *(const float4*)(wp + (k + 3) * DOUT);
            float4 x0 = *(const float4*)(&s_xs[(r0 + 0) * XSP + k]);
            float4 x1 = *(const float4*)(&s_xs[(r0 + 1) * XSP + k]);
            float4 x2 = *(const float4*)(&s_xs[(r0 + 2) * XSP + k]);
            float4 x3 = *(const float4*)(&s_xs[(r0 + 3) * XSP + k]);
            ROWFMA(acc0, x0)
            ROWFMA(acc1, x1)
            ROWFMA(acc2, x2)
            ROWFMA(acc3, x3)
            float4 x4 = *(const float4*)(&s_xs[(r0 + 4) * XSP + k]);
            float4 x5 = *(const float4*)(&s_xs[(r0 + 5) * XSP + k]);
            float4 x6 = *(const float4*)(&s_xs[(r0 + 6) * XSP + k]);
            float4 x7 = *(const float4*)(&s_xs[(r0 + 7) * XSP + k]);
            ROWFMA(acc4, x4)
            ROWFMA(acc5, x5)
            ROWFMA(acc6, x6)
            ROWFMA(acc7, x7)
        }
        __syncthreads();
    }
#undef ROWFMA

    if (isY) {
        float4 av[8] = {acc0, acc1, acc2, acc3, acc4, acc5, acc6, acc7};
        #pragma unroll
        for (int r = 0; r < 8; ++r) {
            int row = rowBase + r0 + r;
            if (row < nRows) {
                uint2 pk;
                pk.x = (unsigned)f2bf(av[r].x) | ((unsigned)f2bf(av[r].y) << 16);
                pk.y = (unsigned)f2bf(av[r].z) | ((unsigned)f2bf(av[r].w) << 16);
                *(uint2*)(y + (size_t)row * DOUT + cg * 4) = pk;
            }
        }
    } else {
        const float4 bv = *(const float4*)(bl + cg * 4);
        float4 av[8] = {acc0, acc1, acc2, acc3, acc4, acc5, acc6, acc7};
        #pragma unroll
        for (int r = 0; r < 8; ++r) {
            int row = rowBase + r0 + r;
            if (row < nRows) {
                float4 o;
                o.x = av[r].x + bv.x; o.y = av[r].y + bv.y;
                o.z = av[r].z + bv.z; o.w = av[r].w + bv.w;
                *(float4*)(zout + (size_t)row * DOUT + cg * 4) = o;
            }
        }
    }
}

// ---------------------------------------------------------------------------
// K2 bg_k (unchanged from R15): bucket + gather fused, one 512-thread block
// per bucket (32 dsts, ~1024 entries).  CSR built entirely in LDS; 8 waves
// x 4 rows gather.
// ---------------------------------------------------------------------------
__global__ void __launch_bounds__(512) bg_k(
    const unsigned* __restrict__ gTail, const int* __restrict__ bucketBuf,
    const unsigned short* __restrict__ y,
    float* __restrict__ out, int n_dst)
{
    __shared__ int s_ent[BCAP];
    __shared__ int s_csr[BCAP];
    __shared__ int s_hist[32];
    __shared__ int s_ofs[32];
    __shared__ int s_start[33];
    const int b = blockIdx.x, t = threadIdx.x;
    const int lane = t & 63, wave = t >> 6;

    if (t < 32) s_hist[t] = 0;
    int m = (int)gTail[b]; if (m > BCAP) m = BCAP;
    __syncthreads();

    const int* bb = bucketBuf + (size_t)b * BCAP;   // 16B aligned (BCAP%4==0)
    const int4* bb4 = (const int4*)bb;
    int4* se4 = (int4*)s_ent;
    const int m4 = m >> 2;
    for (int i4 = t; i4 < m4; i4 += 512) {
        int4 e4 = bb4[i4];
        se4[i4] = e4;
        atomicAdd(&s_hist[e4.x & BMSK], 1);
        atomicAdd(&s_hist[e4.y & BMSK], 1);
        atomicAdd(&s_hist[e4.z & BMSK], 1);
        atomicAdd(&s_hist[e4.w & BMSK], 1);
    }
    for (int i = (m4 << 2) + t; i < m; i += 512) {  // <=3 tail entries
        int e = bb[i];
        s_ent[i] = e;
        atomicAdd(&s_hist[e & BMSK], 1);
    }
    __syncthreads();

    if (wave == 0) {                     // 32-lane inclusive scan of hist
        int h = (lane < 32) ? s_hist[lane] : 0;
        int v = h;
        for (int o = 1; o < 32; o <<= 1) {
            int u = __shfl_up(v, o);
            if (lane >= o) v += u;
        }
        if (lane < 32) {
            s_start[lane + 1] = v;       // row starts (exclusive prefix)
            if (lane == 0) s_start[0] = 0;
            s_ofs[lane] = v - h;         // running placement cursor
        }
    }
    __syncthreads();

    for (int i4 = t; i4 < m4; i4 += 512) {          // exact CSR placement in LDS
        int4 e4 = se4[i4];
        int p0 = atomicAdd(&s_ofs[e4.x & BMSK], 1); s_csr[p0] = e4.x >> BSH;
        int p1 = atomicAdd(&s_ofs[e4.y & BMSK], 1); s_csr[p1] = e4.y >> BSH;
        int p2 = atomicAdd(&s_ofs[e4.z & BMSK], 1); s_csr[p2] = e4.z >> BSH;
        int p3 = atomicAdd(&s_ofs[e4.w & BMSK], 1); s_csr[p3] = e4.w >> BSH;
    }
    for (int i = (m4 << 2) + t; i < m; i += 512) {
        int e = s_ent[i];
        int p = atomicAdd(&s_ofs[e & BMSK], 1);
        s_csr[p] = e >> BSH;
    }
    __syncthreads();

    // ---- gather phase: 8 waves x 4 rows, csr from LDS ----
    const int dbase = b << BSH;
    int nloc = n_dst - dbase; if (nloc > 32) nloc = 32;
    const int g  = lane >> 3;            // edge subgroup 0..7
    const int c8 = lane & 7;             // channel octet: ch 8*c8 .. 8*c8+7
    const uint4* yw = (const uint4*)y;   // one y row = 8 uint4

#define ACC8(al, ah, u)                                              \
    al.x += bflo(u.x); al.y += bfhi(u.x);                            \
    al.z += bflo(u.y); al.w += bfhi(u.y);                            \
    ah.x += bflo(u.z); ah.y += bfhi(u.z);                            \
    ah.z += bflo(u.w); ah.w += bfhi(u.w);

    for (int r = wave; r < nloc; r += 8) {
        const int row = dbase + r;
        const int start = s_start[r];
        const int deg = s_start[r + 1] - start;

        const float4 zv0 = *(const float4*)(out + (size_t)row * DOUT + c8 * 8);
        const float4 zv1 = *(const float4*)(out + (size_t)row * DOUT + c8 * 8 + 4);

        float4 a0l = {0,0,0,0}, a0h = {0,0,0,0};
        float4 a1l = {0,0,0,0}, a1h = {0,0,0,0};
        float4 a2l = {0,0,0,0}, a2h = {0,0,0,0};
        float4 a3l = {0,0,0,0}, a3h = {0,0,0,0};

        for (int co = 0; co < deg; co += 64) {
            int rem = deg - co; if (rem > 64) rem = 64;
            int idx = (lane < rem) ? s_csr[start + co + lane] : 0;
            int i = 0;
            for (; i + 32 <= rem; i += 32) {       // full 32-edge step
                int s0 = __shfl(idx, i + g);
                int s1 = __shfl(idx, i + 8 + g);
                int s2 = __shfl(idx, i + 16 + g);
                int s3 = __shfl(idx, i + 24 + g);
                uint4 u0 = yw[(size_t)s0 * 8 + c8];
                uint4 u1 = yw[(size_t)s1 * 8 + c8];
                uint4 u2 = yw[(size_t)s2 * 8 + c8];
                uint4 u3 = yw[(size_t)s3 * 8 + c8];
                ACC8(a0l, a0h, u0)
                ACC8(a1l, a1h, u1)
                ACC8(a2l, a2h, u2)
                ACC8(a3l, a3h, u3)
            }
            for (; i < rem; i += 8) {              // guarded 8-edge tail
                int e = i + g;
                int s0 = __shfl(idx, e);
                if (e < rem) {
                    uint4 u = yw[(size_t)s0 * 8 + c8];
                    ACC8(a0l, a0h, u)
                }
            }
        }

        float4 sl, sh;
        sl.x = (a0l.x + a1l.x) + (a2l.x + a3l.x);
        sl.y = (a0l.y + a1l.y) + (a2l.y + a3l.y);
        sl.z = (a0l.z + a1l.z) + (a2l.z + a3l.z);
        sl.w = (a0l.w + a1l.w) + (a2l.w + a3l.w);
        sh.x = (a0h.x + a1h.x) + (a2h.x + a3h.x);
        sh.y = (a0h.y + a1h.y) + (a2h.y + a3h.y);
        sh.z = (a0h.z + a1h.z) + (a2h.z + a3h.z);
        sh.w = (a0h.w + a1h.w) + (a2h.w + a3h.w);

        #pragma unroll
        for (int o = 32; o >= 8; o >>= 1) {        // reduce edge subgroups
            sl.x += __shfl_xor(sl.x, o); sl.y += __shfl_xor(sl.y, o);
            sl.z += __shfl_xor(sl.z, o); sl.w += __shfl_xor(sl.w, o);
            sh.x += __shfl_xor(sh.x, o); sh.y += __shfl_xor(sh.y, o);
            sh.z += __shfl_xor(sh.z, o); sh.w += __shfl_xor(sh.w, o);
        }

        const float scale = 1.0f / (float)(deg > 0 ? deg : 1);
        float4 v0, v1;
        v0.x = sl.x * scale + zv0.x; v0.y = sl.y * scale + zv0.y;
        v0.z = sl.z * scale + zv0.z; v0.w = sl.w * scale + zv0.w;
        v1.x = sh.x * scale + zv1.x; v1.y = sh.y * scale + zv1.y;
        v1.z = sh.z * scale + zv1.z; v1.w = sh.w * scale + zv1.w;

        float mx = fmaxf(fmaxf(fmaxf(v0.x, v0.y), fmaxf(v0.z, v0.w)),
                         fmaxf(fmaxf(v1.x, v1.y), fmaxf(v1.z, v1.w)));
        for (int o = 4; o >= 1; o >>= 1) mx = fmaxf(mx, __shfl_xor(mx, o));
        float s = expf(v0.x - mx) + expf(v0.y - mx) + expf(v0.z - mx) + expf(v0.w - mx)
                + expf(v1.x - mx) + expf(v1.y - mx) + expf(v1.z - mx) + expf(v1.w - mx);
        for (int o = 4; o >= 1; o >>= 1) s += __shfl_xor(s, o);
        const float lse = mx + logf(s);

        if (lane < 8) {
            float4 o0, o1;
            o0.x = v0.x - lse; o0.y = v0.y - lse; o0.z = v0.z - lse; o0.w = v0.w - lse;
            o1.x = v1.x - lse; o1.y = v1.y - lse; o1.z = v1.z - lse; o1.w = v1.w - lse;
            *(float4*)(out + (size_t)row * DOUT + c8 * 8)     = o0;
            *(float4*)(out + (size_t)row * DOUT + c8 * 8 + 4) = o1;
        }
    }
#undef ACC8
}

extern "C" void kernel_launch(void* const* d_in, const int* in_sizes, int n_in,
                              void* d_out, int out_size, void* d_ws, size_t ws_size,
                              hipStream_t stream)
{
    const float* x  = (const float*)d_in[0];
    const float* Wl = (const float*)d_in[1];
    const float* bl = (const float*)d_in[2];
    const float* Wr = (const float*)d_in[3];
    const int*   ei = (const int*)d_in[4];

    const int E     = in_sizes[4] / 2;     // 1,600,000
    const int n_src = in_sizes[0] / DIN;   // 100,000
    const int n_dst = out_size / DOUT;     // 50,000
    const int nB    = (n_dst + (1 << BSH) - 1) >> BSH;   // 1563

    // ws layout (ints): gTail[2048] | buckets[nB*BCAP] | y(bf16)
    unsigned* gTail = (unsigned*)d_ws;
    int* bucketBuf = (int*)d_ws + 2048;
    unsigned short* yb = (unsigned short*)(bucketBuf + (size_t)nB * BCAP);
    // total ~= 21.2 MB

    hipMemsetAsync(gTail, 0, 2048 * sizeof(unsigned), stream);

    int nFill = (E + 2047) / 2048;         // 782 (8 edges/thread, 256 thr/block)
    int nyb = (n_src + PROWS - 1) / PROWS; // 782
    int nzb = (n_dst + PROWS - 1) / PROWS; // 391
    int total = nFill + nyb + nzb;         // 1955
    // Fill-coverage: need total >= (nFill-1)*P+1.  floor(total/nFill)=2
    // satisfies it (781*2+1=1563 <= 1955); R16's ceil gave P=3 and dropped
    // 130 fill blocks.
    int P = total / nFill; if (P < 1) P = 1;

    build_k<<<total, 256, 0, stream>>>(
        ei, gTail, bucketBuf, x, Wl, bl, Wr, yb, (float*)d_out,
        E, nFill, P, nyb, n_src, n_dst, nB);

    bg_k<<<nB, 512, 0, stream>>>(gTail, bucketBuf, yb, (float*)d_out, n_dst);
}

// Round 18
// 198.821 us; speedup vs baseline: 1.0471x; 1.0471x over previous
//
#include <hip/hip_runtime.h>
#include <math.h>

#define DIN  128
#define DOUT 64
#define PROWS 64    // rows per proj tile (R15 optimum; 128 regressed 65->88us in R17)
#define KS   32     // k-slab depth
#define XSP  36     // x-slab pitch floats (32+4): 144B = 16B-mult, rows spread banks
#define BSH  5      // bucket = dst >> 5 (32 dsts/bucket)
#define BMSK 31
#define BCAP 1344   // entries/bucket: mean 1024, sd ~32 -> +10 sigma pad (mult of 64)

__device__ inline unsigned short f2bf(float f) {          // RNE bf16 round
    unsigned u = __float_as_uint(f);
    u += 0x7fffu + ((u >> 16) & 1u);
    return (unsigned short)(u >> 16);
}
__device__ inline float bflo(unsigned u) { return __uint_as_float(u << 16); }
__device__ inline float bfhi(unsigned u) { return __uint_as_float(u & 0xffff0000u); }

// ---------------------------------------------------------------------------
// K1 fused build_k (EXACT R15 body, 198.8us total measured).  Fill blocks
// interleaved 1-per-P among proj blocks; fill's atomic latency hides under
// proj FMAs.  Proj: 64x64 tile, thread owns 4 rows x 4 ch, k-slab LDS
// staging (W read once per block; R13's 16x L2-redundancy fix).  Five
// restructuring attempts (R5 fusion, R6 prefetch, R14 gload_lds, R16/17
// wide tile) all regressed -- compiler-scheduled 64-row body is the robust
// local optimum.  Coverage: total >= (nFill-1)*P+1 holds (3127 >= 3125).
// ---------------------------------------------------------------------------
__global__ void __launch_bounds__(256) build_k(
    const int* __restrict__ ei, unsigned* __restrict__ gTail,
    int* __restrict__ bucketBuf,
    const float* __restrict__ x, const float* __restrict__ Wl,
    const float* __restrict__ bl, const float* __restrict__ Wr,
    unsigned short* __restrict__ y, float* __restrict__ zout,
    int E, int nFill, int P, int nyb, int n_src, int n_dst, int nB)
{
    __shared__ float s_mem[6144];              // 24KB: fill 3x2048 ints | proj 4352 floats
    const int b = blockIdx.x;
    const int fq = b / P;
    const bool isFill = ((b % P) == 0) && (fq < nFill);

    if (isFill) {
        int* s_i  = (int*)s_mem;
        int* lcnt = s_i;             // [2048]
        int* lpos = s_i + 2048;      // [2048]
        int* s_gb = s_i + 4096;      // [2048]
        const int t = threadIdx.x;
        const int myb = (fq * 256 + t) * 8;
        const bool full = (myb + 8 <= E);
        const bool any  = (myb < E);
        int4 sa, sb4, da, db;
        if (full) {
            sa  = *(const int4*)(ei + myb);
            sb4 = *(const int4*)(ei + myb + 4);
            da  = *(const int4*)(ei + E + myb);
            db  = *(const int4*)(ei + E + myb + 4);
        }
        #pragma unroll
        for (int k = 0; k < 8; ++k) { lcnt[t + k * 256] = 0; lpos[t + k * 256] = 0; }
        __syncthreads();
        if (full) {
            atomicAdd(&lcnt[da.x >> BSH], 1); atomicAdd(&lcnt[da.y >> BSH], 1);
            atomicAdd(&lcnt[da.z >> BSH], 1); atomicAdd(&lcnt[da.w >> BSH], 1);
            atomicAdd(&lcnt[db.x >> BSH], 1); atomicAdd(&lcnt[db.y >> BSH], 1);
            atomicAdd(&lcnt[db.z >> BSH], 1); atomicAdd(&lcnt[db.w >> BSH], 1);
        } else if (any) {
            for (int i = myb; i < E && i < myb + 8; ++i)
                atomicAdd(&lcnt[ei[E + i] >> BSH], 1);
        }
        __syncthreads();
        for (int bk = t; bk < nB; bk += 256)
            s_gb[bk] = (int)atomicAdd(&gTail[bk], (unsigned)lcnt[bk]);
        __syncthreads();
#define PLACE(S, D) { int bk = (D) >> BSH; int p = atomicAdd(&lpos[bk], 1);          \
                      unsigned pos = (unsigned)(s_gb[bk] + p);                        \
                      if (pos < BCAP) bucketBuf[(size_t)bk * BCAP + pos] =            \
                          ((S) << BSH) | ((D) & BMSK); }
        if (full) {
            PLACE(sa.x,  da.x) PLACE(sa.y,  da.y) PLACE(sa.z,  da.z) PLACE(sa.w,  da.w)
            PLACE(sb4.x, db.x) PLACE(sb4.y, db.y) PLACE(sb4.z, db.z) PLACE(sb4.w, db.w)
        } else if (any) {
            for (int i = myb; i < E && i < myb + 8; ++i) {
                int s = ei[i], d = ei[E + i];
                PLACE(s, d)
            }
        }
#undef PLACE
        return;
    }

    // ---- projection: 64 rows x 64 ch per block, k-slab staged (R13 body) ----
    const int fillsBefore = (fq + 1 < nFill) ? (fq + 1) : nFill;
    const int pb = b - fillsBefore;            // dense proj index
    const int t  = threadIdx.x;
    const bool isY = (pb < nyb);
    const int rowBase = (isY ? pb : pb - nyb) * PROWS;
    const int nRows = isY ? n_src : n_dst;
    const float* __restrict__ W = isY ? Wl : Wr;

    float* s_xs = s_mem;                       // [64][XSP]
    float* s_ws = s_mem + PROWS * XSP;         // [KS][DOUT]

    const int cg = t & 15;                     // channel quad: 4cg..4cg+3
    const int rg = t >> 4;                     // row group: rows 4rg..4rg+3
    const int r0 = rg * 4;

    float4 acc0 = {0.f,0.f,0.f,0.f};
    float4 acc1 = {0.f,0.f,0.f,0.f};
    float4 acc2 = {0.f,0.f,0.f,0.f};
    float4 acc3 = {0.f,0.f,0.f,0.f};

#define ROWFMA(acc, xv)                                                                     \
    acc.x = fmaf(xv.w, w3.x, fmaf(xv.z, w2.x, fmaf(xv.y, w1.x, fmaf(xv.x, w0.x, acc.x)))); \
    acc.y = fmaf(xv.w, w3.y, fmaf(xv.z, w2.y, fmaf(xv.y, w1.y, fmaf(xv.x, w0.y, acc.y)))); \
    acc.z = fmaf(xv.w, w3.z, fmaf(xv.z, w2.z, fmaf(xv.y, w1.z, fmaf(xv.x, w0.z, acc.z)))); \
    acc.w = fmaf(xv.w, w3.w, fmaf(xv.z, w2.w, fmaf(xv.y, w1.w, fmaf(xv.x, w0.w, acc.w))));

    for (int k0 = 0; k0 < DIN; k0 += KS) {
        // stage x slab: 64 rows x 32 k = 512 float4 (8 lanes x 128B per row)
        {
            const float* xs = x + (size_t)rowBase * DIN + k0;
            #pragma unroll
            for (int j = 0; j < 2; ++j) {
                int fi = t + 256 * j;          // 0..511
                int row = fi >> 3, c4 = fi & 7;
                if (rowBase + row < nRows) {
                    float4 v = *(const float4*)(xs + (size_t)row * DIN + c4 * 4);
                    *(float4*)(&s_xs[row * XSP + c4 * 4]) = v;
                }
            }
            // stage w slab: 32 k x 64 ch = 512 float4 (16 lanes x 256B per k)
            const float* ws = W + (size_t)k0 * DOUT;
            #pragma unroll
            for (int j = 0; j < 2; ++j) {
                int fi = t + 256 * j;
                int row = fi >> 4, c4 = fi & 15;
                float4 v = *(const float4*)(ws + row * DOUT + c4 * 4);
                *(float4*)(&s_ws[row * DOUT + c4 * 4]) = v;
            }
        }
        __syncthreads();

        const float* wp = s_ws + cg * 4;
        #pragma unroll 2
        for (int k = 0; k < KS; k += 4) {
            float4 w0 = *(const float4*)(wp + (k + 0) * DOUT);
            float4 w1 = *(const float4*)(wp + (k + 1) * DOUT);
            float4 w2 = *(const float4*)(wp + (k + 2) * DOUT);
            float4 w3 = *(const float4*)(wp + (k + 3) * DOUT);
            float4 x0 = *(const float4*)(&s_xs[(r0 + 0) * XSP + k]);
            float4 x1 = *(const float4*)(&s_xs[(r0 + 1) * XSP + k]);
            float4 x2 = *(const float4*)(&s_xs[(r0 + 2) * XSP + k]);
            float4 x3 = *(const float4*)(&s_xs[(r0 + 3) * XSP + k]);
            ROWFMA(acc0, x0)
            ROWFMA(acc1, x1)
            ROWFMA(acc2, x2)
            ROWFMA(acc3, x3)
        }
        __syncthreads();
    }
#undef ROWFMA

    if (isY) {
        float4 av[4] = {acc0, acc1, acc2, acc3};
        #pragma unroll
        for (int r = 0; r < 4; ++r) {
            int row = rowBase + r0 + r;
            if (row < nRows) {
                uint2 pk;
                pk.x = (unsigned)f2bf(av[r].x) | ((unsigned)f2bf(av[r].y) << 16);
                pk.y = (unsigned)f2bf(av[r].z) | ((unsigned)f2bf(av[r].w) << 16);
                *(uint2*)(y + (size_t)row * DOUT + cg * 4) = pk;
            }
        }
    } else {
        const float4 bv = *(const float4*)(bl + cg * 4);
        float4 av[4] = {acc0, acc1, acc2, acc3};
        #pragma unroll
        for (int r = 0; r < 4; ++r) {
            int row = rowBase + r0 + r;
            if (row < nRows) {
                float4 o;
                o.x = av[r].x + bv.x; o.y = av[r].y + bv.y;
                o.z = av[r].z + bv.z; o.w = av[r].w + bv.w;
                *(float4*)(zout + (size_t)row * DOUT + cg * 4) = o;
            }
        }
    }
}

// ---------------------------------------------------------------------------
// K2 bg_k (EXACT R15 body): bucket + gather fused, one 512-thread block per
// bucket (32 dsts, ~1024 entries).  CSR built entirely in LDS; 8 waves x 4
// rows gather.
// ---------------------------------------------------------------------------
__global__ void __launch_bounds__(512) bg_k(
    const unsigned* __restrict__ gTail, const int* __restrict__ bucketBuf,
    const unsigned short* __restrict__ y,
    float* __restrict__ out, int n_dst)
{
    __shared__ int s_ent[BCAP];
    __shared__ int s_csr[BCAP];
    __shared__ int s_hist[32];
    __shared__ int s_ofs[32];
    __shared__ int s_start[33];
    const int b = blockIdx.x, t = threadIdx.x;
    const int lane = t & 63, wave = t >> 6;

    if (t < 32) s_hist[t] = 0;
    int m = (int)gTail[b]; if (m > BCAP) m = BCAP;
    __syncthreads();

    const int* bb = bucketBuf + (size_t)b * BCAP;   // 16B aligned (BCAP%4==0)
    const int4* bb4 = (const int4*)bb;
    int4* se4 = (int4*)s_ent;
    const int m4 = m >> 2;
    for (int i4 = t; i4 < m4; i4 += 512) {
        int4 e4 = bb4[i4];
        se4[i4] = e4;
        atomicAdd(&s_hist[e4.x & BMSK], 1);
        atomicAdd(&s_hist[e4.y & BMSK], 1);
        atomicAdd(&s_hist[e4.z & BMSK], 1);
        atomicAdd(&s_hist[e4.w & BMSK], 1);
    }
    for (int i = (m4 << 2) + t; i < m; i += 512) {  // <=3 tail entries
        int e = bb[i];
        s_ent[i] = e;
        atomicAdd(&s_hist[e & BMSK], 1);
    }
    __syncthreads();

    if (wave == 0) {                     // 32-lane inclusive scan of hist
        int h = (lane < 32) ? s_hist[lane] : 0;
        int v = h;
        for (int o = 1; o < 32; o <<= 1) {
            int u = __shfl_up(v, o);
            if (lane >= o) v += u;
        }
        if (lane < 32) {
            s_start[lane + 1] = v;       // row starts (exclusive prefix)
            if (lane == 0) s_start[0] = 0;
            s_ofs[lane] = v - h;         // running placement cursor
        }
    }
    __syncthreads();

    for (int i4 = t; i4 < m4; i4 += 512) {          // exact CSR placement in LDS
        int4 e4 = se4[i4];
        int p0 = atomicAdd(&s_ofs[e4.x & BMSK], 1); s_csr[p0] = e4.x >> BSH;
        int p1 = atomicAdd(&s_ofs[e4.y & BMSK], 1); s_csr[p1] = e4.y >> BSH;
        int p2 = atomicAdd(&s_ofs[e4.z & BMSK], 1); s_csr[p2] = e4.z >> BSH;
        int p3 = atomicAdd(&s_ofs[e4.w & BMSK], 1); s_csr[p3] = e4.w >> BSH;
    }
    for (int i = (m4 << 2) + t; i < m; i += 512) {
        int e = s_ent[i];
        int p = atomicAdd(&s_ofs[e & BMSK], 1);
        s_csr[p] = e >> BSH;
    }
    __syncthreads();

    // ---- gather phase: 8 waves x 4 rows, csr from LDS ----
    const int dbase = b << BSH;
    int nloc = n_dst - dbase; if (nloc > 32) nloc = 32;
    const int g  = lane >> 3;            // edge subgroup 0..7
    const int c8 = lane & 7;             // channel octet: ch 8*c8 .. 8*c8+7
    const uint4* yw = (const uint4*)y;   // one y row = 8 uint4

#define ACC8(al, ah, u)                                              \
    al.x += bflo(u.x); al.y += bfhi(u.x);                            \
    al.z += bflo(u.y); al.w += bfhi(u.y);                            \
    ah.x += bflo(u.z); ah.y += bfhi(u.z);                            \
    ah.z += bflo(u.w); ah.w += bfhi(u.w);

    for (int r = wave; r < nloc; r += 8) {
        const int row = dbase + r;
        const int start = s_start[r];
        const int deg = s_start[r + 1] - start;

        const float4 zv0 = *(const float4*)(out + (size_t)row * DOUT + c8 * 8);
        const float4 zv1 = *(const float4*)(out + (size_t)row * DOUT + c8 * 8 + 4);

        float4 a0l = {0,0,0,0}, a0h = {0,0,0,0};
        float4 a1l = {0,0,0,0}, a1h = {0,0,0,0};
        float4 a2l = {0,0,0,0}, a2h = {0,0,0,0};
        float4 a3l = {0,0,0,0}, a3h = {0,0,0,0};

        for (int co = 0; co < deg; co += 64) {
            int rem = deg - co; if (rem > 64) rem = 64;
            int idx = (lane < rem) ? s_csr[start + co + lane] : 0;
            int i = 0;
            for (; i + 32 <= rem; i += 32) {       // full 32-edge step
                int s0 = __shfl(idx, i + g);
                int s1 = __shfl(idx, i + 8 + g);
                int s2 = __shfl(idx, i + 16 + g);
                int s3 = __shfl(idx, i + 24 + g);
                uint4 u0 = yw[(size_t)s0 * 8 + c8];
                uint4 u1 = yw[(size_t)s1 * 8 + c8];
                uint4 u2 = yw[(size_t)s2 * 8 + c8];
                uint4 u3 = yw[(size_t)s3 * 8 + c8];
                ACC8(a0l, a0h, u0)
                ACC8(a1l, a1h, u1)
                ACC8(a2l, a2h, u2)
                ACC8(a3l, a3h, u3)
            }
            for (; i < rem; i += 8) {              // guarded 8-edge tail
                int e = i + g;
                int s0 = __shfl(idx, e);
                if (e < rem) {
                    uint4 u = yw[(size_t)s0 * 8 + c8];
                    ACC8(a0l, a0h, u)
                }
            }
        }

        float4 sl, sh;
        sl.x = (a0l.x + a1l.x) + (a2l.x + a3l.x);
        sl.y = (a0l.y + a1l.y) + (a2l.y + a3l.y);
        sl.z = (a0l.z + a1l.z) + (a2l.z + a3l.z);
        sl.w = (a0l.w + a1l.w) + (a2l.w + a3l.w);
        sh.x = (a0h.x + a1h.x) + (a2h.x + a3h.x);
        sh.y = (a0h.y + a1h.y) + (a2h.y + a3h.y);
        sh.z = (a0h.z + a1h.z) + (a2h.z + a3h.z);
        sh.w = (a0h.w + a1h.w) + (a2h.w + a3h.w);

        #pragma unroll
        for (int o = 32; o >= 8; o >>= 1) {        // reduce edge subgroups
            sl.x += __shfl_xor(sl.x, o); sl.y += __shfl_xor(sl.y, o);
            sl.z += __shfl_xor(sl.z, o); sl.w += __shfl_xor(sl.w, o);
            sh.x += __shfl_xor(sh.x, o); sh.y += __shfl_xor(sh.y, o);
            sh.z += __shfl_xor(sh.z, o); sh.w += __shfl_xor(sh.w, o);
        }

        const float scale = 1.0f / (float)(deg > 0 ? deg : 1);
        float4 v0, v1;
        v0.x = sl.x * scale + zv0.x; v0.y = sl.y * scale + zv0.y;
        v0.z = sl.z * scale + zv0.z; v0.w = sl.w * scale + zv0.w;
        v1.x = sh.x * scale + zv1.x; v1.y = sh.y * scale + zv1.y;
        v1.z = sh.z * scale + zv1.z; v1.w = sh.w * scale + zv1.w;

        float mx = fmaxf(fmaxf(fmaxf(v0.x, v0.y), fmaxf(v0.z, v0.w)),
                         fmaxf(fmaxf(v1.x, v1.y), fmaxf(v1.z, v1.w)));
        for (int o = 4; o >= 1; o >>= 1) mx = fmaxf(mx, __shfl_xor(mx, o));
        float s = expf(v0.x - mx) + expf(v0.y - mx) + expf(v0.z - mx) + expf(v0.w - mx)
                + expf(v1.x - mx) + expf(v1.y - mx) + expf(v1.z - mx) + expf(v1.w - mx);
        for (int o = 4; o >= 1; o >>= 1) s += __shfl_xor(s, o);
        const float lse = mx + logf(s);

        if (lane < 8) {
            float4 o0, o1;
            o0.x = v0.x - lse; o0.y = v0.y - lse; o0.z = v0.z - lse; o0.w = v0.w - lse;
            o1.x = v1.x - lse; o1.y = v1.y - lse; o1.z = v1.z - lse; o1.w = v1.w - lse;
            *(float4*)(out + (size_t)row * DOUT + c8 * 8)     = o0;
            *(float4*)(out + (size_t)row * DOUT + c8 * 8 + 4) = o1;
        }
    }
#undef ACC8
}

extern "C" void kernel_launch(void* const* d_in, const int* in_sizes, int n_in,
                              void* d_out, int out_size, void* d_ws, size_t ws_size,
                              hipStream_t stream)
{
    const float* x  = (const float*)d_in[0];
    const float* Wl = (const float*)d_in[1];
    const float* bl = (const float*)d_in[2];
    const float* Wr = (const float*)d_in[3];
    const int*   ei = (const int*)d_in[4];

    const int E     = in_sizes[4] / 2;     // 1,600,000
    const int n_src = in_sizes[0] / DIN;   // 100,000
    const int n_dst = out_size / DOUT;     // 50,000
    const int nB    = (n_dst + (1 << BSH) - 1) >> BSH;   // 1563

    // ws layout (ints): gTail[2048] | buckets[nB*BCAP] | y(bf16)
    unsigned* gTail = (unsigned*)d_ws;
    int* bucketBuf = (int*)d_ws + 2048;
    unsigned short* yb = (unsigned short*)(bucketBuf + (size_t)nB * BCAP);
    // total ~= 21.2 MB

    hipMemsetAsync(gTail, 0, 2048 * sizeof(unsigned), stream);

    int nFill = (E + 2047) / 2048;         // 782 (8 edges/thread, 256 thr/block)
    int nyb = (n_src + PROWS - 1) / PROWS; // 1563
    int nzb = (n_dst + PROWS - 1) / PROWS; // 782
    int total = nFill + nyb + nzb;         // 3127
    int P = (total + nFill - 1) / nFill;   // 4; coverage: 3127 >= 781*4+1 = 3125
    if (total < (nFill - 1) * P + 1) P = total / nFill;  // safety (holds for these sizes)

    build_k<<<total, 256, 0, stream>>>(
        ei, gTail, bucketBuf, x, Wl, bl, Wr, yb, (float*)d_out,
        E, nFill, P, nyb, n_src, n_dst, nB);

    bg_k<<<nB, 512, 0, stream>>>(gTail, bucketBuf, yb, (float*)d_out, n_dst);
}